// Round 14
// baseline (308.961 us; speedup 1.0000x reference)
//
#include <hip/hip_runtime.h>
#include <cmath>

#define NB 256   // batch
#define NT 512   // seq len
#define ND 50    // emb dim
#define NH 50    // hidden
#define NC 5     // classes

typedef float f32x4 __attribute__((ext_vector_type(4)));
typedef float f32x2 __attribute__((ext_vector_type(2)));

__device__ __forceinline__ float rcpf(float x) { return __builtin_amdgcn_rcpf(x); }
// readlane: uniform result -> SGPR; lane index compile-time const
__device__ __forceinline__ float rdl(float v, int l) {
    return __int_as_float(__builtin_amdgcn_readlane(__float_as_int(v), l));
}
// asm loads: non-rematerializable. ONLY on 16B-aligned addresses (52-float padded rows).
__device__ __forceinline__ void gload4(f32x4& d, const float* p) {
    asm volatile("global_load_dwordx4 %0, %1, off" : "=v"(d) : "v"(p));
}

#define FENCE_BAR                                             \
    asm volatile("s_waitcnt lgkmcnt(0)" ::: "memory");        \
    __builtin_amdgcn_s_barrier();                             \
    asm volatile("" ::: "memory");

// ---------------- K0: repack weights into padded [200][52] rows (16B-aligned) ------------
__global__ __launch_bounds__(256)
void k0_prep(const float* __restrict__ W_hh, const float* __restrict__ W_ih,
             float* __restrict__ wsWih, float* __restrict__ wsWhh)
{
    int idx = blockIdx.x * 256 + threadIdx.x;
    if (idx < 200 * 52) {
        int d = idx / 52, c = idx - (idx / 52) * 52;
        wsWih[idx] = (c < ND) ? W_ih[d * ND + c] : 0.f;
    } else if (idx < 2 * 200 * 52) {
        int j = idx - 200 * 52;
        int d = j / 52, c = j - (j / 52) * 52;
        wsWhh[j] = (c < NH) ? W_hh[d * NH + c] : 0.f;
    }
}

#define DECLROW(P) f32x4 P##_0{},P##_1{},P##_2{},P##_3{},P##_4{},P##_5{},P##_6{},P##_7{}, \
                         P##_8{},P##_9{},P##_10{},P##_11{},P##_12{};
#define LOADROW(P,B) { const float* b_=(B); \
    gload4(P##_0,b_+0);  gload4(P##_1,b_+4);  gload4(P##_2,b_+8);  gload4(P##_3,b_+12); \
    gload4(P##_4,b_+16); gload4(P##_5,b_+20); gload4(P##_6,b_+24); gload4(P##_7,b_+28); \
    gload4(P##_8,b_+32); gload4(P##_9,b_+36); gload4(P##_10,b_+40); gload4(P##_11,b_+44); \
    gload4(P##_12,b_+48); }

// ---------------- K2: fused producer+scan, 8 waves, UNIFORM barriers ----------------------
// Scan (waves 0-3): R13's bitwise-gold path verbatim.
// Producers (waves 4-7): k1's bitwise-gold row dot (4 scalar chains, stride-4, pads zero).
#define FMA2(H,W,A) __builtin_elementwise_fma((H),(W),(A))
#define CDOT1(SEED,OUT) { f32x2 A01 = {(SEED), 0.f}, A23 = {0.f, 0.f};        \
    A01=FMA2(hp0 ,CW_0.xy ,A01); A23=FMA2(hp1 ,CW_0.zw ,A23);                 \
    A01=FMA2(hp2 ,CW_1.xy ,A01); A23=FMA2(hp3 ,CW_1.zw ,A23);                 \
    A01=FMA2(hp4 ,CW_2.xy ,A01); A23=FMA2(hp5 ,CW_2.zw ,A23);                 \
    A01=FMA2(hp6 ,CW_3.xy ,A01); A23=FMA2(hp7 ,CW_3.zw ,A23);                 \
    A01=FMA2(hp8 ,CW_4.xy ,A01); A23=FMA2(hp9 ,CW_4.zw ,A23);                 \
    A01=FMA2(hp10,CW_5.xy ,A01); A23=FMA2(hp11,CW_5.zw ,A23);                 \
    A01=FMA2(hp12,CW_6.xy ,A01); A23=FMA2(hp13,CW_6.zw ,A23);                 \
    A01=FMA2(hp14,CW_7.xy ,A01); A23=FMA2(hp15,CW_7.zw ,A23);                 \
    A01=FMA2(hp16,CW_8.xy ,A01); A23=FMA2(hp17,CW_8.zw ,A23);                 \
    A01=FMA2(hp18,CW_9.xy ,A01); A23=FMA2(hp19,CW_9.zw ,A23);                 \
    A01=FMA2(hp20,CW_10.xy,A01); A23=FMA2(hp21,CW_10.zw,A23);                 \
    A01=FMA2(hp22,CW_11.xy,A01); A23=FMA2(hp23,CW_11.zw,A23);                 \
    A23=FMA2(hp24,CW_12.xy,A23);                                              \
    OUT = (A01.x + A01.y) + (A23.x + A23.y); }

// producer row dot: k1's exact order (a0..a3 stride-4 chains; tuple 12 covers 48..51, pads 0)
#define PT(J,EV) a0=fmaf(rdl(EV,4*J+0),CW_##J.x,a0); a1=fmaf(rdl(EV,4*J+1),CW_##J.y,a1); \
                 a2=fmaf(rdl(EV,4*J+2),CW_##J.z,a2); a3=fmaf(rdl(EV,4*J+3),CW_##J.w,a3);
#define PRODROW(EV,SLOT) { float a0=bq,a1=0.f,a2=0.f,a3=0.f;                  \
    PT(0,EV) PT(1,EV) PT(2,EV) PT(3,EV) PT(4,EV) PT(5,EV) PT(6,EV)            \
    PT(7,EV) PT(8,EV) PT(9,EV) PT(10,EV) PT(11,EV) PT(12,EV)                  \
    float xpv = (a0 + a1) + (a2 + a3);                                        \
    if (kln < NH) ring[(SLOT) & 15][pw][kln] = xpv; }

// one step: scan step S + produce slot S+8 + prefetch e row S+12. ONE uniform barrier.
#define STEPF(EI, S) {                                                        \
    if (isScan) {                                                             \
        float xq = ring[(S) & 15][wid][kln];                                  \
        f32x2 hp0 ={rdl(hv,0 ),rdl(hv,1 )}, hp1 ={rdl(hv,2 ),rdl(hv,3 )};     \
        f32x2 hp2 ={rdl(hv,4 ),rdl(hv,5 )}, hp3 ={rdl(hv,6 ),rdl(hv,7 )};     \
        f32x2 hp4 ={rdl(hv,8 ),rdl(hv,9 )}, hp5 ={rdl(hv,10),rdl(hv,11)};     \
        f32x2 hp6 ={rdl(hv,12),rdl(hv,13)}, hp7 ={rdl(hv,14),rdl(hv,15)};     \
        f32x2 hp8 ={rdl(hv,16),rdl(hv,17)}, hp9 ={rdl(hv,18),rdl(hv,19)};     \
        f32x2 hp10={rdl(hv,20),rdl(hv,21)}, hp11={rdl(hv,22),rdl(hv,23)};     \
        f32x2 hp12={rdl(hv,24),rdl(hv,25)}, hp13={rdl(hv,26),rdl(hv,27)};     \
        f32x2 hp14={rdl(hv,28),rdl(hv,29)}, hp15={rdl(hv,30),rdl(hv,31)};     \
        f32x2 hp16={rdl(hv,32),rdl(hv,33)}, hp17={rdl(hv,34),rdl(hv,35)};     \
        f32x2 hp18={rdl(hv,36),rdl(hv,37)}, hp19={rdl(hv,38),rdl(hv,39)};     \
        f32x2 hp20={rdl(hv,40),rdl(hv,41)}, hp21={rdl(hv,42),rdl(hv,43)};     \
        f32x2 hp22={rdl(hv,44),rdl(hv,45)}, hp23={rdl(hv,46),rdl(hv,47)};     \
        f32x2 hp24={rdl(hv,48),rdl(hv,49)};                                   \
        float gg;                                                             \
        CDOT1(xq, gg)                                                         \
        float act = fmaf(rcpf(1.f + __expf(-sce * gg)), sce, ade);            \
        abuf[(S) & 1][wid][kln] = act;                                        \
    } else if ((S) + 8 < NT) {                                                \
        PRODROW(EI, (S) + 8)                                                  \
        int tN = (S) + 12; if (tN > NT - 1) tN = NT - 1;                      \
        EI = (kln < NH) ? emb_table[(size_t)xls[tN] * ND + kln] : 0.f;        \
    }                                                                         \
    FENCE_BAR                                                                 \
    if (isScan) {                                                             \
        float i_ = abuf[(S) & 1][0][kln];                                     \
        float f_ = abuf[(S) & 1][1][kln];                                     \
        float gt = abuf[(S) & 1][2][kln];                                     \
        float o_ = abuf[(S) & 1][3][kln];                                     \
        cst = fmaf(f_, cst, i_ * gt);                                         \
        float th = fmaf(rcpf(1.f + __expf(-2.f * cst)), 2.f, -1.f);           \
        hv = o_ * th;                                                         \
        hkeep = ((S) == lastidx) ? hv : hkeep;                                \
    }                                                                         \
}

__global__ __launch_bounds__(512)
__attribute__((amdgpu_waves_per_eu(2, 2)))   // 8 waves, 2/SIMD, 256-VGPR budget each
void k2_fused(const int* __restrict__ x, const int* __restrict__ lengths,
              const float* __restrict__ emb_table,
              const float* __restrict__ wsWih, const float* __restrict__ wsWhh,
              const float* __restrict__ b_ih, const float* __restrict__ b_hh,
              float* __restrict__ lastH)
{
    const int b   = blockIdx.x, tid = threadIdx.x;
    const int wid = tid >> 6;                  // 0-3 scan gate q; 4-7 producer gate pw
    const int kln = tid & 63;
    const int kc  = (kln < NH) ? kln : NH - 1;
    const bool isScan = wid < 4;
    const int  pw  = wid & 3;

    __shared__ __align__(16) float ring[16][4][64];  // xp ring: [slot][gate][unit] 16KB
    __shared__ __align__(16) float abuf[2][4][64];   // act exchange (parity dbuf)    2KB
    __shared__ int xls[NT];                          // token ids                     2KB

    xls[tid] = x[(size_t)b * NT + tid];              // 512 threads exactly
    __syncthreads();

    const int lastidx = min(lengths[b], NT) - 1;

    // role-specific weight row (uniform per wave), one 13x dwordx4 register set
    const float* wrow = isScan ? (wsWhh + ((size_t)wid * NH + kc) * 52)
                               : (wsWih + ((size_t)pw  * NH + kc) * 52);
    DECLROW(CW)
    LOADROW(CW, wrow)
    float bq = 0.f;
    if (!isScan) bq = b_ih[pw * NH + kc] + b_hh[pw * NH + kc];
    asm volatile("s_waitcnt vmcnt(0)" ::: "memory");
    __builtin_amdgcn_sched_barrier(0);

    const float sce = (wid == 2) ? 2.f : 1.f;        // scan gate g: tanh via sigmoid
    const float ade = (wid == 2) ? -1.f : 0.f;

    float hv = 0.f, cst = 0.f, hkeep = 0.f;

    // ---- prologue: produce ring slots 0..7 (uniform barrier each iteration) ----
    for (int p = 0; p < 8; ++p) {
        if (!isScan) {
            int xt = xls[p];
            float ev = (kln < NH) ? emb_table[(size_t)xt * ND + kln] : 0.f;
            PRODROW(ev, p)
        }
        FENCE_BAR
    }
    // e prefetch rotation: rows 8..11
    float e0 = 0.f, e1 = 0.f, e2 = 0.f, e3 = 0.f;
    if (!isScan && kln < NH) {
        e0 = emb_table[(size_t)xls[8]  * ND + kln];
        e1 = emb_table[(size_t)xls[9]  * ND + kln];
        e2 = emb_table[(size_t)xls[10] * ND + kln];
        e3 = emb_table[(size_t)xls[11] * ND + kln];
    }

    // ---- main loop: 512 steps, one uniform barrier per step ----
    for (int s4 = 0; s4 < NT; s4 += 4) {
        STEPF(e0, s4 + 0)
        STEPF(e1, s4 + 1)
        STEPF(e2, s4 + 2)
        STEPF(e3, s4 + 3)
    }

    if (wid == 0 && kln < NH) lastH[b * NH + kln] = hkeep;
}

// ---------------- K3: pooling + concat + linear (unchanged — proven) ---------------------
__global__ __launch_bounds__(256)
void k3_final(const int* __restrict__ x, const int* __restrict__ lengths,
              const float* __restrict__ emb_table,
              const float* __restrict__ W_lin, const float* __restrict__ b_lin,
              const float* __restrict__ lastH, float* __restrict__ out)
{
    const int b = blockIdx.x, tid = threadIdx.x;
    __shared__ int xv[NT];
    __shared__ float ps[5][52], pm[5][52];
    __shared__ float rep[160];

    for (int i = tid; i < NT; i += 256) xv[i] = x[(size_t)b * NT + i];
    __syncthreads();
    const int g = tid / ND, d = tid - g * ND;
    if (tid < 250) {
        float s = 0.f, m = -INFINITY;
        #pragma unroll 4
        for (int t = g; t < NT; t += 5) {
            float e = emb_table[(size_t)xv[t] * ND + d];
            s += e; m = fmaxf(m, e);
        }
        ps[g][d] = s; pm[g][d] = m;
    }
    __syncthreads();
    if (tid < NH) {
        float s = ps[0][tid] + ps[1][tid] + ps[2][tid] + ps[3][tid] + ps[4][tid];
        float m = fmaxf(fmaxf(fmaxf(pm[0][tid], pm[1][tid]), fmaxf(pm[2][tid], pm[3][tid])), pm[4][tid]);
        rep[tid]          = lastH[b * NH + tid];
        rep[NH + tid]     = s / (float)lengths[b];
        rep[2 * NH + tid] = m;
    }
    __syncthreads();
    if (tid < NC) {
        float acc = b_lin[tid];
        #pragma unroll 5
        for (int j = 0; j < 3 * NH; ++j)
            acc = fmaf(rep[j], W_lin[tid * 3 * NH + j], acc);
        out[(size_t)b * NC + tid] = acc;
    }
}

extern "C" void kernel_launch(void* const* d_in, const int* in_sizes, int n_in,
                              void* d_out, int out_size, void* d_ws, size_t ws_size,
                              hipStream_t stream) {
    const int*   x     = (const int*)d_in[0];
    const int*   len   = (const int*)d_in[1];
    const float* emb   = (const float*)d_in[3];
    const float* W_ih  = (const float*)d_in[4];
    const float* W_hh  = (const float*)d_in[5];
    const float* b_ih  = (const float*)d_in[6];
    const float* b_hh  = (const float*)d_in[7];
    const float* W_lin = (const float*)d_in[8];
    const float* b_lin = (const float*)d_in[9];
    float* outp = (float*)d_out;

    // ws: lastH[256*50] @0 | wsWih[200*52] @64KB | wsWhh[200*52] after
    float* lastH = (float*)d_ws;
    float* wsWih = (float*)((char*)d_ws + 64 * 1024);
    float* wsWhh = wsWih + 200 * 52;

    hipLaunchKernelGGL(k0_prep, dim3(82), dim3(256), 0, stream, W_hh, W_ih, wsWih, wsWhh);
    hipLaunchKernelGGL(k2_fused, dim3(NB), dim3(512), 0, stream,
                       x, len, emb, wsWih, wsWhh, b_ih, b_hh, lastH);
    hipLaunchKernelGGL(k3_final, dim3(NB), dim3(256), 0, stream,
                       x, len, emb, W_lin, b_lin, lastH, outp);
}

// Round 15
// 300.556 us; speedup vs baseline: 1.0280x; 1.0280x over previous
//
#include <hip/hip_runtime.h>
#include <cmath>

#define NB 256   // batch
#define NT 512   // seq len
#define ND 50    // emb dim
#define NH 50    // hidden
#define NC 5     // classes

typedef float f32x4 __attribute__((ext_vector_type(4)));
typedef float f32x2 __attribute__((ext_vector_type(2)));

__device__ __forceinline__ float rcpf(float x) { return __builtin_amdgcn_rcpf(x); }
// readlane: uniform result -> SGPR; lane index compile-time const
__device__ __forceinline__ float rdl(float v, int l) {
    return __int_as_float(__builtin_amdgcn_readlane(__float_as_int(v), l));
}
// asm loads: non-rematerializable. ONLY on 16B-aligned addresses (52-float padded rows).
__device__ __forceinline__ void gload4(f32x4& d, const float* p) {
    asm volatile("global_load_dwordx4 %0, %1, off" : "=v"(d) : "v"(p));
}

#define FENCE_BAR                                             \
    asm volatile("s_waitcnt lgkmcnt(0)" ::: "memory");        \
    __builtin_amdgcn_s_barrier();                             \
    asm volatile("" ::: "memory");

// ---------------- K0: repack weights into padded [200][52] rows (16B-aligned) ------------
__global__ __launch_bounds__(256)
void k0_prep(const float* __restrict__ W_hh, const float* __restrict__ W_ih,
             float* __restrict__ wsWih, float* __restrict__ wsWhh)
{
    int idx = blockIdx.x * 256 + threadIdx.x;
    if (idx < 200 * 52) {
        int d = idx / 52, c = idx - (idx / 52) * 52;
        wsWih[idx] = (c < ND) ? W_ih[d * ND + c] : 0.f;
    } else if (idx < 2 * 200 * 52) {
        int j = idx - 200 * 52;
        int d = j / 52, c = j - (j / 52) * 52;
        wsWhh[j] = (c < NH) ? W_hh[d * NH + c] : 0.f;
    }
}

#define DECLROW(P) f32x4 P##_0{},P##_1{},P##_2{},P##_3{},P##_4{},P##_5{},P##_6{},P##_7{}, \
                         P##_8{},P##_9{},P##_10{},P##_11{},P##_12{};
#define LOADROW(P,B) { const float* b_=(B); \
    gload4(P##_0,b_+0);  gload4(P##_1,b_+4);  gload4(P##_2,b_+8);  gload4(P##_3,b_+12); \
    gload4(P##_4,b_+16); gload4(P##_5,b_+20); gload4(P##_6,b_+24); gload4(P##_7,b_+28); \
    gload4(P##_8,b_+32); gload4(P##_9,b_+36); gload4(P##_10,b_+40); gload4(P##_11,b_+44); \
    gload4(P##_12,b_+48); }

// k1 dot: gold order (13 tuples over the zero-padded row; pads are exact no-ops)
#define DOTI(J, HP) { f32x4 h4 = (HP)[J];                          \
    a0 = fmaf(h4.x, w##J.x, a0); a1 = fmaf(h4.y, w##J.y, a1);     \
    a2 = fmaf(h4.z, w##J.z, a2); a3 = fmaf(h4.w, w##J.w, a3); }
#define DOTI13(HP) DOTI(0,HP) DOTI(1,HP) DOTI(2,HP) DOTI(3,HP) DOTI(4,HP) DOTI(5,HP) \
    DOTI(6,HP) DOTI(7,HP) DOTI(8,HP) DOTI(9,HP) DOTI(10,HP) DOTI(11,HP) DOTI(12,HP)

// ---------------- K1: xp[b,t,4u+g] = W_ih[g*50+u] . emb[x[b,t]] + b_ih + b_hh ------------
// (verbatim proven structure from rounds 5/7/10-13)
__global__ __launch_bounds__(256)
void k1_xproj(const int* __restrict__ x, const int* __restrict__ lengths,
              const float* __restrict__ emb_table,
              const float* __restrict__ wsWih, const float* __restrict__ b_ih,
              const float* __restrict__ b_hh,
              float* __restrict__ xp, int t0, int t1, int tiles, int tcAlloc)
{
    const int b    = blockIdx.x / tiles;
    const int tile = blockIdx.x % tiles;
    const int rt0  = t0 + tile * 64;
    if (rt0 >= t1) return;
    if (rt0 >= lengths[b]) return;            // rows past length are never consumed
    const int nrows = min(64, t1 - rt0);

    __shared__ int xv[64];
    __shared__ __align__(16) float eL[64][52];

    const int tid = threadIdx.x;

    float bsum = 0.f;
    const float* wrow = wsWih + tid * 52;
    f32x4 w0{},w1{},w2{},w3{},w4{},w5{},w6{},w7{},w8{},w9{},w10{},w11{},w12{};
    gload4(w0,wrow+0); gload4(w1,wrow+4); gload4(w2,wrow+8); gload4(w3,wrow+12);
    gload4(w4,wrow+16); gload4(w5,wrow+20); gload4(w6,wrow+24); gload4(w7,wrow+28);
    gload4(w8,wrow+32); gload4(w9,wrow+36); gload4(w10,wrow+40); gload4(w11,wrow+44);
    gload4(w12,wrow+48);
    if (tid < 200) bsum = b_ih[tid] + b_hh[tid];
    if (tid < nrows) xv[tid] = x[(size_t)b * NT + rt0 + tid];
    __syncthreads();
    for (int idx = tid; idx < nrows * 52; idx += 256) {
        int row = idx / 52, col = idx - row * 52;
        eL[row][col] = (col < ND) ? emb_table[(size_t)xv[row] * ND + col] : 0.f;
    }
    asm volatile("s_waitcnt vmcnt(0)" ::: "memory");  // weights resident
    __builtin_amdgcn_sched_barrier(0);
    __syncthreads();
    if (tid < 200) {
        const int wr = 4 * (tid % NH) + (tid / NH);   // quad-permuted position
        float* xpb = xp + ((size_t)b * tcAlloc + (rt0 - t0)) * 200 + wr;
        for (int row = 0; row < nrows; ++row) {
            const f32x4* ep = (const f32x4*)&eL[row][0];
            float a0 = bsum, a1 = 0.f, a2 = 0.f, a3 = 0.f;
            DOTI13(ep)
            xpb[(size_t)row * 200] = (a0 + a1) + (a2 + a3);
        }
    }
}

// ---------------- K2: 2 waves x 2 gates/lane — rdl amortized, 2-wave barrier -------------
// gate dot, bitwise-gold (== R13's absmax-0.0 CDOT): A01=(a0,a1) over j%4∈{0,1},
// A23=(a2,a3) over j%4∈{2,3}, tails h48->a2/h49->a3, combine (a0+a1)+(a2+a3).
#define FMA2(H,W,A) __builtin_elementwise_fma((H),(W),(A))
#define CDOTP(P,SEED,OUT) { f32x2 A01 = {(SEED), 0.f}, A23 = {0.f, 0.f};      \
    A01=FMA2(hp0 ,P##_0.xy ,A01); A23=FMA2(hp1 ,P##_0.zw ,A23);               \
    A01=FMA2(hp2 ,P##_1.xy ,A01); A23=FMA2(hp3 ,P##_1.zw ,A23);               \
    A01=FMA2(hp4 ,P##_2.xy ,A01); A23=FMA2(hp5 ,P##_2.zw ,A23);               \
    A01=FMA2(hp6 ,P##_3.xy ,A01); A23=FMA2(hp7 ,P##_3.zw ,A23);               \
    A01=FMA2(hp8 ,P##_4.xy ,A01); A23=FMA2(hp9 ,P##_4.zw ,A23);               \
    A01=FMA2(hp10,P##_5.xy ,A01); A23=FMA2(hp11,P##_5.zw ,A23);               \
    A01=FMA2(hp12,P##_6.xy ,A01); A23=FMA2(hp13,P##_6.zw ,A23);               \
    A01=FMA2(hp14,P##_7.xy ,A01); A23=FMA2(hp15,P##_7.zw ,A23);               \
    A01=FMA2(hp16,P##_8.xy ,A01); A23=FMA2(hp17,P##_8.zw ,A23);               \
    A01=FMA2(hp18,P##_9.xy ,A01); A23=FMA2(hp19,P##_9.zw ,A23);               \
    A01=FMA2(hp20,P##_10.xy,A01); A23=FMA2(hp21,P##_10.zw,A23);               \
    A01=FMA2(hp22,P##_11.xy,A01); A23=FMA2(hp23,P##_11.zw,A23);               \
    A23=FMA2(hp24,P##_12.xy,A23);                                             \
    OUT = (A01.x + A01.y) + (A23.x + A23.y); }

// One step. Uniform control flow for both waves (barrier legality).
// acts double-buffered by step parity: write(s+1) never races read(s).
#define SSTEP(XQ, S) {                                                        \
    f32x2 hp0 ={rdl(hv,0 ),rdl(hv,1 )}, hp1 ={rdl(hv,2 ),rdl(hv,3 )};         \
    f32x2 hp2 ={rdl(hv,4 ),rdl(hv,5 )}, hp3 ={rdl(hv,6 ),rdl(hv,7 )};         \
    f32x2 hp4 ={rdl(hv,8 ),rdl(hv,9 )}, hp5 ={rdl(hv,10),rdl(hv,11)};         \
    f32x2 hp6 ={rdl(hv,12),rdl(hv,13)}, hp7 ={rdl(hv,14),rdl(hv,15)};         \
    f32x2 hp8 ={rdl(hv,16),rdl(hv,17)}, hp9 ={rdl(hv,18),rdl(hv,19)};         \
    f32x2 hp10={rdl(hv,20),rdl(hv,21)}, hp11={rdl(hv,22),rdl(hv,23)};         \
    f32x2 hp12={rdl(hv,24),rdl(hv,25)}, hp13={rdl(hv,26),rdl(hv,27)};         \
    f32x2 hp14={rdl(hv,28),rdl(hv,29)}, hp15={rdl(hv,30),rdl(hv,31)};         \
    f32x2 hp16={rdl(hv,32),rdl(hv,33)}, hp17={rdl(hv,34),rdl(hv,35)};         \
    f32x2 hp18={rdl(hv,36),rdl(hv,37)}, hp19={rdl(hv,38),rdl(hv,39)};         \
    f32x2 hp20={rdl(hv,40),rdl(hv,41)}, hp21={rdl(hv,42),rdl(hv,43)};         \
    f32x2 hp22={rdl(hv,44),rdl(hv,45)}, hp23={rdl(hv,46),rdl(hv,47)};         \
    f32x2 hp24={rdl(hv,48),rdl(hv,49)};                                       \
    float gA, gB;                                                             \
    CDOTP(WA, XQ.x, gA)                                                       \
    CDOTP(WB, XQ.y, gB)                                                       \
    { int sn_ = (S) + 4; if (sn_ > nsteps - 1) sn_ = nsteps - 1;              \
      XQ = *(const f32x2*)&xpb[(size_t)sn_ * 200]; }                          \
    float actA = fmaf(rcpf(1.f + __expf(-sce * gA)), sce, ade);               \
    float actB = fmaf(rcpf(1.f + __expf(-gB)), 1.f, 0.f);                     \
    abuf[(S) & 1][wid][kln] = (f32x2){actA, actB};                            \
    FENCE_BAR                                                                 \
    f32x2 if_ = abuf[(S) & 1][0][kln];   /* (i, f) */                         \
    f32x2 go_ = abuf[(S) & 1][1][kln];   /* (g, o) */                         \
    cst = fmaf(if_.y, cst, if_.x * go_.x);                                    \
    float th = fmaf(rcpf(1.f + __expf(-2.f * cst)), 2.f, -1.f);               \
    hv = go_.y * th;                                                          \
    hkeep = (t0 + (S) == lastidx) ? hv : hkeep;                               \
}

__global__ __launch_bounds__(128)
__attribute__((amdgpu_waves_per_eu(1, 1)))   // 2 waves on 2 SIMDs, full budgets
void k2_scan(const int* __restrict__ lengths, const float* __restrict__ wsWhh,
             const float* __restrict__ xp,
             float* __restrict__ stH, float* __restrict__ stC, float* __restrict__ lastH,
             int t0, int t1, int tcAlloc)
{
    const int b   = blockIdx.x, tid = threadIdx.x;
    const int wid = tid >> 6;                  // 0: gates (i,f)   1: gates (g,o)
    const int kln = tid & 63;                  // lane = hidden unit
    const int kc  = (kln < NH) ? kln : NH - 1; // lanes 50-63 shadow unit 49 (harmless dup)

    __shared__ __align__(16) f32x2 abuf[2][2][64];  // [parity][wave][lane] act pairs, 2KB

    const int lastidx = min(lengths[b], NT) - 1;
    const int nsteps  = t1 - t0;

    // both waves hold identical (hv, cst) per lane -> h broadcast stays in-wave (readlane)
    float hv  = (t0 == 0) ? 0.f : stH[b * NH + kc];
    float cst = (t0 == 0) ? 0.f : stC[b * NH + kc];

    // weights: TWO gate rows = 26 aligned dwordx4 = 104 VGPRs (h-pairs live in SGPRs)
    DECLROW(WA) DECLROW(WB)
    LOADROW(WA, wsWhh + ((size_t)(2 * wid + 0) * NH + kc) * 52)
    LOADROW(WB, wsWhh + ((size_t)(2 * wid + 1) * NH + kc) * 52)
    asm volatile("s_waitcnt vmcnt(0)" ::: "memory");
    __builtin_amdgcn_sched_barrier(0);

    const float sce = (wid == 1) ? 2.f : 1.f;      // wave1 gate-A is g: tanh via sigmoid
    const float ade = (wid == 1) ? -1.f : 0.f;     // fma(r,1,0)==r bitwise for sigmoids

    // xq: f32x2 per step (quad-permuted slots 4k+2w, 4k+2w+1), 4-deep compiler rotation
    const float* xpb = xp + (size_t)b * tcAlloc * 200 + 4 * kc + 2 * wid;
    f32x2 xq0 = *(const f32x2*)&xpb[0];
    f32x2 xq1 = *(const f32x2*)&xpb[200];
    f32x2 xq2 = *(const f32x2*)&xpb[400];
    f32x2 xq3 = *(const f32x2*)&xpb[600];
    float hkeep = 0.f;

    for (int s4 = 0; s4 < nsteps; s4 += 4) {
        SSTEP(xq0, s4 + 0)
        SSTEP(xq1, s4 + 1)
        SSTEP(xq2, s4 + 2)
        SSTEP(xq3, s4 + 3)
    }

    if (wid == 0 && kln < NH) {
        stH[b * NH + kln] = hv;
        stC[b * NH + kln] = cst;
        if (lastidx >= t0 && lastidx < t1) lastH[b * NH + kln] = hkeep;
    }
}

// ---------------- K3: pooling + concat + linear (unchanged — proven) ---------------------
__global__ __launch_bounds__(256)
void k3_final(const int* __restrict__ x, const int* __restrict__ lengths,
              const float* __restrict__ emb_table,
              const float* __restrict__ W_lin, const float* __restrict__ b_lin,
              const float* __restrict__ lastH, float* __restrict__ out)
{
    const int b = blockIdx.x, tid = threadIdx.x;
    __shared__ int xv[NT];
    __shared__ float ps[5][52], pm[5][52];
    __shared__ float rep[160];

    for (int i = tid; i < NT; i += 256) xv[i] = x[(size_t)b * NT + i];
    __syncthreads();
    const int g = tid / ND, d = tid - g * ND;
    if (tid < 250) {
        float s = 0.f, m = -INFINITY;
        #pragma unroll 4
        for (int t = g; t < NT; t += 5) {
            float e = emb_table[(size_t)xv[t] * ND + d];
            s += e; m = fmaxf(m, e);
        }
        ps[g][d] = s; pm[g][d] = m;
    }
    __syncthreads();
    if (tid < NH) {
        float s = ps[0][tid] + ps[1][tid] + ps[2][tid] + ps[3][tid] + ps[4][tid];
        float m = fmaxf(fmaxf(fmaxf(pm[0][tid], pm[1][tid]), fmaxf(pm[2][tid], pm[3][tid])), pm[4][tid]);
        rep[tid]          = lastH[b * NH + tid];
        rep[NH + tid]     = s / (float)lengths[b];
        rep[2 * NH + tid] = m;
    }
    __syncthreads();
    if (tid < NC) {
        float acc = b_lin[tid];
        #pragma unroll 5
        for (int j = 0; j < 3 * NH; ++j)
            acc = fmaf(rep[j], W_lin[tid * 3 * NH + j], acc);
        out[(size_t)b * NC + tid] = acc;
    }
}

extern "C" void kernel_launch(void* const* d_in, const int* in_sizes, int n_in,
                              void* d_out, int out_size, void* d_ws, size_t ws_size,
                              hipStream_t stream) {
    const int*   x     = (const int*)d_in[0];
    const int*   len   = (const int*)d_in[1];
    const float* emb   = (const float*)d_in[3];
    const float* W_ih  = (const float*)d_in[4];
    const float* W_hh  = (const float*)d_in[5];
    const float* b_ih  = (const float*)d_in[6];
    const float* b_hh  = (const float*)d_in[7];
    const float* W_lin = (const float*)d_in[8];
    const float* b_lin = (const float*)d_in[9];
    float* outp = (float*)d_out;

    // ws: [stH][stC][lastH] | @160KB: wsWih[200*52], wsWhh[200*52] | @256KB: xp (+8KB slack)
    float* stH   = (float*)d_ws;
    float* stC   = stH + NB * NH;
    float* lastH = stC + NB * NH;
    float* wsWih = (float*)((char*)d_ws + 160 * 1024);
    float* wsWhh = wsWih + 200 * 52;
    const size_t xpOff = 256 * 1024;
    float* xp = (float*)((char*)d_ws + xpOff);

    size_t avail = (ws_size > xpOff + 8192) ? ws_size - xpOff - 8192 : 0;
    int tc = (int)(avail / ((size_t)NB * 200 * sizeof(float)));
    tc &= ~3;                 // chunks are multiples of 4 (NT=512 -> every chunk too)
    if (tc > NT) tc = NT;
    if (tc < 4)  tc = 4;

    hipLaunchKernelGGL(k0_prep, dim3(82), dim3(256), 0, stream, W_hh, W_ih, wsWih, wsWhh);

    for (int t0 = 0; t0 < NT; t0 += tc) {
        const int t1 = min(NT, t0 + tc);
        const int tiles = (t1 - t0 + 63) / 64;
        hipLaunchKernelGGL(k1_xproj, dim3(NB * tiles), dim3(256), 0, stream,
                           x, len, emb, wsWih, b_ih, b_hh, xp, t0, t1, tiles, tc);
        hipLaunchKernelGGL(k2_scan, dim3(NB), dim3(128), 0, stream,
                           len, wsWhh, xp, stH, stC, lastH, t0, t1, tc);
    }
    hipLaunchKernelGGL(k3_final, dim3(NB), dim3(256), 0, stream,
                       x, len, emb, W_lin, b_lin, lastH, outp);
}

// Round 16
// 254.022 us; speedup vs baseline: 1.2163x; 1.1832x over previous
//
#include <hip/hip_runtime.h>
#include <cmath>

#define NB 256   // batch
#define NT 512   // seq len
#define ND 50    // emb dim
#define NH 50    // hidden
#define NC 5     // classes

typedef float f32x4 __attribute__((ext_vector_type(4)));
typedef float f32x2 __attribute__((ext_vector_type(2)));

__device__ __forceinline__ float rcpf(float x) { return __builtin_amdgcn_rcpf(x); }
// readlane: uniform result -> SGPR; lane index compile-time const
__device__ __forceinline__ float rdl(float v, int l) {
    return __int_as_float(__builtin_amdgcn_readlane(__float_as_int(v), l));
}
// asm loads: non-rematerializable. ONLY on 16B-aligned addresses (52-float padded rows).
__device__ __forceinline__ void gload4(f32x4& d, const float* p) {
    asm volatile("global_load_dwordx4 %0, %1, off" : "=v"(d) : "v"(p));
}

#define FENCE_BAR                                             \
    asm volatile("s_waitcnt lgkmcnt(0)" ::: "memory");        \
    __builtin_amdgcn_s_barrier();                             \
    asm volatile("" ::: "memory");

// ---------------- K0: repack weights into padded [200][52] rows (16B-aligned) ------------
__global__ __launch_bounds__(256)
void k0_prep(const float* __restrict__ W_hh, const float* __restrict__ W_ih,
             float* __restrict__ wsWih, float* __restrict__ wsWhh)
{
    int idx = blockIdx.x * 256 + threadIdx.x;
    if (idx < 200 * 52) {
        int d = idx / 52, c = idx - (idx / 52) * 52;
        wsWih[idx] = (c < ND) ? W_ih[d * ND + c] : 0.f;
    } else if (idx < 2 * 200 * 52) {
        int j = idx - 200 * 52;
        int d = j / 52, c = j - (j / 52) * 52;
        wsWhh[j] = (c < NH) ? W_hh[d * NH + c] : 0.f;
    }
}

#define DECLROW(P) f32x4 P##_0{},P##_1{},P##_2{},P##_3{},P##_4{},P##_5{},P##_6{},P##_7{}, \
                         P##_8{},P##_9{},P##_10{},P##_11{},P##_12{};
#define LOADROW(P,B) { const float* b_=(B); \
    gload4(P##_0,b_+0);  gload4(P##_1,b_+4);  gload4(P##_2,b_+8);  gload4(P##_3,b_+12); \
    gload4(P##_4,b_+16); gload4(P##_5,b_+20); gload4(P##_6,b_+24); gload4(P##_7,b_+28); \
    gload4(P##_8,b_+32); gload4(P##_9,b_+36); gload4(P##_10,b_+40); gload4(P##_11,b_+44); \
    gload4(P##_12,b_+48); }

// ---------------- K1: xp via SCALAR e-broadcast (zero LDS, zero barriers) ----------------
// e row is wave-uniform per row -> readfirstlane'd pointer -> s_load; one scalar-pair
// operand per v_pk_fma_f32 (same mechanism R13's scan proved with readlane h-pairs).
// Bitwise-gold chains: A01=(a0,a1): seed bsum, j%4 in {0,1}, tail e48->a0/e49->a1;
// A23=(a2,a3): j%4 in {2,3}. Omitted pad-FMAs were exact fma(0,0,acc) no-ops.
#define FMA2(H,W,A) __builtin_elementwise_fma((H),(W),(A))
#define KP(J) { f32x2 eA = ep[2*(J)], eB = ep[2*(J)+1];                       \
    A01 = FMA2(eA, w##J.xy, A01); A23 = FMA2(eB, w##J.zw, A23); }

__global__ __launch_bounds__(256)
void k1_xproj(const int* __restrict__ x, const int* __restrict__ lengths,
              const float* __restrict__ emb_table,
              const float* __restrict__ wsWih, const float* __restrict__ b_ih,
              const float* __restrict__ b_hh,
              float* __restrict__ xp, int t0, int t1, int tiles, int tcAlloc)
{
    const int b    = blockIdx.x / tiles;
    const int tile = blockIdx.x % tiles;
    const int rt0  = t0 + tile * 64;
    if (rt0 >= t1) return;
    if (rt0 >= lengths[b]) return;            // rows past length are never consumed
    const int nrows = min(64, t1 - rt0);

    const int tid = threadIdx.x;
    const int* xrow = x + (size_t)b * NT + rt0;    // uniform base

    float bsum = 0.f;
    const float* wrow = wsWih + tid * 52;
    f32x4 w0{},w1{},w2{},w3{},w4{},w5{},w6{},w7{},w8{},w9{},w10{},w11{},w12{};
    gload4(w0,wrow+0); gload4(w1,wrow+4); gload4(w2,wrow+8); gload4(w3,wrow+12);
    gload4(w4,wrow+16); gload4(w5,wrow+20); gload4(w6,wrow+24); gload4(w7,wrow+28);
    gload4(w8,wrow+32); gload4(w9,wrow+36); gload4(w10,wrow+40); gload4(w11,wrow+44);
    gload4(w12,wrow+48);
    if (tid < 200) bsum = b_ih[tid] + b_hh[tid];
    asm volatile("s_waitcnt vmcnt(0)" ::: "memory");  // weights resident
    __builtin_amdgcn_sched_barrier(0);

    if (tid < 200) {
        const int wr = 4 * (tid % NH) + (tid / NH);   // quad-permuted position
        float* xpb = xp + ((size_t)b * tcAlloc + (rt0 - t0)) * 200 + wr;
        for (int row = 0; row < nrows; ++row) {
            int xr = __builtin_amdgcn_readfirstlane(xrow[row]);   // uniform token id
            const f32x2* ep = (const f32x2*)(emb_table + (size_t)xr * ND); // 8B-aligned
            f32x2 A01 = {bsum, 0.f}, A23 = {0.f, 0.f};
            KP(0) KP(1) KP(2) KP(3) KP(4) KP(5) KP(6) KP(7) KP(8) KP(9) KP(10) KP(11)
            A01 = FMA2(ep[24], w12.xy, A01);          // tail: e48->a0, e49->a1
            xpb[(size_t)row * 200] = (A01.x + A01.y) + (A23.x + A23.y);
        }
    }
}

// ---------------- K2: 4 waves x 1 gate/lane — R13 verbatim (182 us, absmax 0.0) ----------
#define CDOT1(SEED,OUT) { f32x2 A01 = {(SEED), 0.f}, A23 = {0.f, 0.f};        \
    A01=FMA2(hp0 ,CW_0.xy ,A01); A23=FMA2(hp1 ,CW_0.zw ,A23);                 \
    A01=FMA2(hp2 ,CW_1.xy ,A01); A23=FMA2(hp3 ,CW_1.zw ,A23);                 \
    A01=FMA2(hp4 ,CW_2.xy ,A01); A23=FMA2(hp5 ,CW_2.zw ,A23);                 \
    A01=FMA2(hp6 ,CW_3.xy ,A01); A23=FMA2(hp7 ,CW_3.zw ,A23);                 \
    A01=FMA2(hp8 ,CW_4.xy ,A01); A23=FMA2(hp9 ,CW_4.zw ,A23);                 \
    A01=FMA2(hp10,CW_5.xy ,A01); A23=FMA2(hp11,CW_5.zw ,A23);                 \
    A01=FMA2(hp12,CW_6.xy ,A01); A23=FMA2(hp13,CW_6.zw ,A23);                 \
    A01=FMA2(hp14,CW_7.xy ,A01); A23=FMA2(hp15,CW_7.zw ,A23);                 \
    A01=FMA2(hp16,CW_8.xy ,A01); A23=FMA2(hp17,CW_8.zw ,A23);                 \
    A01=FMA2(hp18,CW_9.xy ,A01); A23=FMA2(hp19,CW_9.zw ,A23);                 \
    A01=FMA2(hp20,CW_10.xy,A01); A23=FMA2(hp21,CW_10.zw,A23);                 \
    A01=FMA2(hp22,CW_11.xy,A01); A23=FMA2(hp23,CW_11.zw,A23);                 \
    A23=FMA2(hp24,CW_12.xy,A23);                                              \
    OUT = (A01.x + A01.y) + (A23.x + A23.y); }

#define SSTEP(XQ, S) {                                                        \
    f32x2 hp0 ={rdl(hv,0 ),rdl(hv,1 )}, hp1 ={rdl(hv,2 ),rdl(hv,3 )};         \
    f32x2 hp2 ={rdl(hv,4 ),rdl(hv,5 )}, hp3 ={rdl(hv,6 ),rdl(hv,7 )};         \
    f32x2 hp4 ={rdl(hv,8 ),rdl(hv,9 )}, hp5 ={rdl(hv,10),rdl(hv,11)};         \
    f32x2 hp6 ={rdl(hv,12),rdl(hv,13)}, hp7 ={rdl(hv,14),rdl(hv,15)};         \
    f32x2 hp8 ={rdl(hv,16),rdl(hv,17)}, hp9 ={rdl(hv,18),rdl(hv,19)};         \
    f32x2 hp10={rdl(hv,20),rdl(hv,21)}, hp11={rdl(hv,22),rdl(hv,23)};         \
    f32x2 hp12={rdl(hv,24),rdl(hv,25)}, hp13={rdl(hv,26),rdl(hv,27)};         \
    f32x2 hp14={rdl(hv,28),rdl(hv,29)}, hp15={rdl(hv,30),rdl(hv,31)};         \
    f32x2 hp16={rdl(hv,32),rdl(hv,33)}, hp17={rdl(hv,34),rdl(hv,35)};         \
    f32x2 hp18={rdl(hv,36),rdl(hv,37)}, hp19={rdl(hv,38),rdl(hv,39)};         \
    f32x2 hp20={rdl(hv,40),rdl(hv,41)}, hp21={rdl(hv,42),rdl(hv,43)};         \
    f32x2 hp22={rdl(hv,44),rdl(hv,45)}, hp23={rdl(hv,46),rdl(hv,47)};         \
    f32x2 hp24={rdl(hv,48),rdl(hv,49)};                                       \
    float gg;                                                                 \
    CDOT1(XQ, gg)                                                             \
    { int sn_ = (S) + 4; if (sn_ > nsteps - 1) sn_ = nsteps - 1;              \
      XQ = xpb[(size_t)sn_ * 200]; }                                          \
    float act = fmaf(rcpf(1.f + __expf(-sce * gg)), sce, ade);                \
    abuf[(S) & 1][wid][kln] = act;                                            \
    FENCE_BAR                                                                 \
    float i_ = abuf[(S) & 1][0][kln];                                         \
    float f_ = abuf[(S) & 1][1][kln];                                         \
    float gt = abuf[(S) & 1][2][kln];                                         \
    float o_ = abuf[(S) & 1][3][kln];                                         \
    cst = fmaf(f_, cst, i_ * gt);                                             \
    float th = fmaf(rcpf(1.f + __expf(-2.f * cst)), 2.f, -1.f);               \
    hv = o_ * th;                                                             \
    hkeep = (t0 + (S) == lastidx) ? hv : hkeep;                               \
}

__global__ __launch_bounds__(256)
__attribute__((amdgpu_waves_per_eu(1, 1)))   // 4 waves -> 1 per SIMD, full budgets
void k2_scan(const int* __restrict__ lengths, const float* __restrict__ wsWhh,
             const float* __restrict__ xp,
             float* __restrict__ stH, float* __restrict__ stC, float* __restrict__ lastH,
             int t0, int t1, int tcAlloc)
{
    const int b   = blockIdx.x, tid = threadIdx.x;
    const int wid = tid >> 6;                  // gate q: 0=i 1=f 2=g 3=o
    const int kln = tid & 63;                  // lane = hidden unit
    const int kc  = (kln < NH) ? kln : NH - 1; // lanes 50-63 shadow unit 49 (harmless dup)

    __shared__ __align__(16) float abuf[2][4][64];  // [parity][gate][lane] acts, 2KB

    const int lastidx = min(lengths[b], NT) - 1;
    const int nsteps  = t1 - t0;

    // all 4 waves hold identical (hv, cst) per lane -> h broadcast stays in-wave (readlane)
    float hv  = (t0 == 0) ? 0.f : stH[b * NH + kc];
    float cst = (t0 == 0) ? 0.f : stC[b * NH + kc];

    // weights: ONE gate row = 13 aligned dwordx4 = 52 VGPRs (fits under the ~132 cap)
    DECLROW(CW)
    LOADROW(CW, wsWhh + ((size_t)wid * NH + kc) * 52)
    asm volatile("s_waitcnt vmcnt(0)" ::: "memory");
    __builtin_amdgcn_sched_barrier(0);

    const float sce = (wid == 2) ? 2.f : 1.f;      // gate g: tanh(x)=2*sigmoid(2x)-1
    const float ade = (wid == 2) ? -1.f : 0.f;     // sigmoid: fma(r,1,0)==r bitwise

    // xq: one float per step (quad-permuted slot 4k+q), 4-deep compiler rotation
    const float* xpb = xp + (size_t)b * tcAlloc * 200 + 4 * kc + wid;
    float xq0 = xpb[0];
    float xq1 = xpb[200];
    float xq2 = xpb[400];
    float xq3 = xpb[600];
    float hkeep = 0.f;

    for (int s4 = 0; s4 < nsteps; s4 += 4) {
        SSTEP(xq0, s4 + 0)
        SSTEP(xq1, s4 + 1)
        SSTEP(xq2, s4 + 2)
        SSTEP(xq3, s4 + 3)
    }

    if (wid == 0 && kln < NH) {
        stH[b * NH + kln] = hv;
        stC[b * NH + kln] = cst;
        if (lastidx >= t0 && lastidx < t1) lastH[b * NH + kln] = hkeep;
    }
}

// ---------------- K3: pooling + concat + linear (unchanged — proven) ---------------------
__global__ __launch_bounds__(256)
void k3_final(const int* __restrict__ x, const int* __restrict__ lengths,
              const float* __restrict__ emb_table,
              const float* __restrict__ W_lin, const float* __restrict__ b_lin,
              const float* __restrict__ lastH, float* __restrict__ out)
{
    const int b = blockIdx.x, tid = threadIdx.x;
    __shared__ int xv[NT];
    __shared__ float ps[5][52], pm[5][52];
    __shared__ float rep[160];

    for (int i = tid; i < NT; i += 256) xv[i] = x[(size_t)b * NT + i];
    __syncthreads();
    const int g = tid / ND, d = tid - g * ND;
    if (tid < 250) {
        float s = 0.f, m = -INFINITY;
        #pragma unroll 4
        for (int t = g; t < NT; t += 5) {
            float e = emb_table[(size_t)xv[t] * ND + d];
            s += e; m = fmaxf(m, e);
        }
        ps[g][d] = s; pm[g][d] = m;
    }
    __syncthreads();
    if (tid < NH) {
        float s = ps[0][tid] + ps[1][tid] + ps[2][tid] + ps[3][tid] + ps[4][tid];
        float m = fmaxf(fmaxf(fmaxf(pm[0][tid], pm[1][tid]), fmaxf(pm[2][tid], pm[3][tid])), pm[4][tid]);
        rep[tid]          = lastH[b * NH + tid];
        rep[NH + tid]     = s / (float)lengths[b];
        rep[2 * NH + tid] = m;
    }
    __syncthreads();
    if (tid < NC) {
        float acc = b_lin[tid];
        #pragma unroll 5
        for (int j = 0; j < 3 * NH; ++j)
            acc = fmaf(rep[j], W_lin[tid * 3 * NH + j], acc);
        out[(size_t)b * NC + tid] = acc;
    }
}

extern "C" void kernel_launch(void* const* d_in, const int* in_sizes, int n_in,
                              void* d_out, int out_size, void* d_ws, size_t ws_size,
                              hipStream_t stream) {
    const int*   x     = (const int*)d_in[0];
    const int*   len   = (const int*)d_in[1];
    const float* emb   = (const float*)d_in[3];
    const float* W_ih  = (const float*)d_in[4];
    const float* W_hh  = (const float*)d_in[5];
    const float* b_ih  = (const float*)d_in[6];
    const float* b_hh  = (const float*)d_in[7];
    const float* W_lin = (const float*)d_in[8];
    const float* b_lin = (const float*)d_in[9];
    float* outp = (float*)d_out;

    // ws: [stH][stC][lastH] | @160KB: wsWih[200*52], wsWhh[200*52] | @256KB: xp (+8KB slack)
    float* stH   = (float*)d_ws;
    float* stC   = stH + NB * NH;
    float* lastH = stC + NB * NH;
    float* wsWih = (float*)((char*)d_ws + 160 * 1024);
    float* wsWhh = wsWih + 200 * 52;
    const size_t xpOff = 256 * 1024;
    float* xp = (float*)((char*)d_ws + xpOff);

    size_t avail = (ws_size > xpOff + 8192) ? ws_size - xpOff - 8192 : 0;
    int tc = (int)(avail / ((size_t)NB * 200 * sizeof(float)));
    tc &= ~3;                 // chunks are multiples of 4 (NT=512 -> every chunk too)
    if (tc > NT) tc = NT;
    if (tc < 4)  tc = 4;

    hipLaunchKernelGGL(k0_prep, dim3(82), dim3(256), 0, stream, W_hh, W_ih, wsWih, wsWhh);

    for (int t0 = 0; t0 < NT; t0 += tc) {
        const int t1 = min(NT, t0 + tc);
        const int tiles = (t1 - t0 + 63) / 64;
        hipLaunchKernelGGL(k1_xproj, dim3(NB * tiles), dim3(256), 0, stream,
                           x, len, emb, wsWih, b_ih, b_hh, xp, t0, t1, tiles, tc);
        hipLaunchKernelGGL(k2_scan, dim3(NB), dim3(256), 0, stream,
                           len, wsWhh, xp, stH, stC, lastH, t0, t1, tc);
    }
    hipLaunchKernelGGL(k3_final, dim3(NB), dim3(256), 0, stream,
                       x, len, emb, W_lin, b_lin, lastH, outp);
}

// Round 17
// 248.974 us; speedup vs baseline: 1.2409x; 1.0203x over previous
//
#include <hip/hip_runtime.h>
#include <cmath>

#define NB 256   // batch
#define NT 512   // seq len
#define ND 50    // emb dim
#define NH 50    // hidden
#define NC 5     // classes

typedef float f32x4 __attribute__((ext_vector_type(4)));
typedef float f32x2 __attribute__((ext_vector_type(2)));

__device__ __forceinline__ float rcpf(float x) { return __builtin_amdgcn_rcpf(x); }
// readlane: uniform result -> SGPR; lane index compile-time const
__device__ __forceinline__ float rdl(float v, int l) {
    return __int_as_float(__builtin_amdgcn_readlane(__float_as_int(v), l));
}
// asm loads: non-rematerializable. ONLY on 16B-aligned addresses (52-float padded rows).
__device__ __forceinline__ void gload4(f32x4& d, const float* p) {
    asm volatile("global_load_dwordx4 %0, %1, off" : "=v"(d) : "v"(p));
}

#define FENCE_BAR                                             \
    asm volatile("s_waitcnt lgkmcnt(0)" ::: "memory");        \
    __builtin_amdgcn_s_barrier();                             \
    asm volatile("" ::: "memory");

// ---------------- K0: repack weights into padded [200][52] rows (16B-aligned) ------------
__global__ __launch_bounds__(256)
void k0_prep(const float* __restrict__ W_hh, const float* __restrict__ W_ih,
             float* __restrict__ wsWih, float* __restrict__ wsWhh)
{
    int idx = blockIdx.x * 256 + threadIdx.x;
    if (idx < 200 * 52) {
        int d = idx / 52, c = idx - (idx / 52) * 52;
        wsWih[idx] = (c < ND) ? W_ih[d * ND + c] : 0.f;
    } else if (idx < 2 * 200 * 52) {
        int j = idx - 200 * 52;
        int d = j / 52, c = j - (j / 52) * 52;
        wsWhh[j] = (c < NH) ? W_hh[d * NH + c] : 0.f;
    }
}

#define DECLROW(P) f32x4 P##_0{},P##_1{},P##_2{},P##_3{},P##_4{},P##_5{},P##_6{},P##_7{}, \
                         P##_8{},P##_9{},P##_10{},P##_11{},P##_12{};
#define LOADROW(P,B) { const float* b_=(B); \
    gload4(P##_0,b_+0);  gload4(P##_1,b_+4);  gload4(P##_2,b_+8);  gload4(P##_3,b_+12); \
    gload4(P##_4,b_+16); gload4(P##_5,b_+20); gload4(P##_6,b_+24); gload4(P##_7,b_+28); \
    gload4(P##_8,b_+32); gload4(P##_9,b_+36); gload4(P##_10,b_+40); gload4(P##_11,b_+44); \
    gload4(P##_12,b_+48); }

// ---------------- K1: xp via SCALAR e-broadcast, 2-row batched + token prefetch ----------
// Per-row chains bitwise == R16 (A01 seed bsum, j%4∈{0,1}; A23 j%4∈{2,3}; tail e48/e49->A01).
#define FMA2(H,W,A) __builtin_elementwise_fma((H),(W),(A))
#define KP2(J) { f32x2 a_=e0[2*(J)], b_=e0[2*(J)+1], c_=e1[2*(J)], d_=e1[2*(J)+1]; \
    A01=FMA2(a_,w##J.xy,A01); A23=FMA2(b_,w##J.zw,A23);                            \
    B01=FMA2(c_,w##J.xy,B01); B23=FMA2(d_,w##J.zw,B23); }

__global__ __launch_bounds__(256)
void k1_xproj(const int* __restrict__ x, const int* __restrict__ lengths,
              const float* __restrict__ emb_table,
              const float* __restrict__ wsWih, const float* __restrict__ b_ih,
              const float* __restrict__ b_hh,
              float* __restrict__ xp, int t0, int t1, int tiles, int tcAlloc)
{
    const int b    = blockIdx.x / tiles;
    const int tile = blockIdx.x % tiles;
    const int rt0  = t0 + tile * 64;
    if (rt0 >= t1) return;
    if (rt0 >= lengths[b]) return;            // rows past length are never consumed
    const int nrows = min(64, t1 - rt0);      // multiple of 4 -> even

    const int tid = threadIdx.x;
    const int* xrow = x + (size_t)b * NT + rt0;    // uniform base

    float bsum = 0.f;
    const float* wrow = wsWih + tid * 52;
    f32x4 w0{},w1{},w2{},w3{},w4{},w5{},w6{},w7{},w8{},w9{},w10{},w11{},w12{};
    gload4(w0,wrow+0); gload4(w1,wrow+4); gload4(w2,wrow+8); gload4(w3,wrow+12);
    gload4(w4,wrow+16); gload4(w5,wrow+20); gload4(w6,wrow+24); gload4(w7,wrow+28);
    gload4(w8,wrow+32); gload4(w9,wrow+36); gload4(w10,wrow+40); gload4(w11,wrow+44);
    gload4(w12,wrow+48);
    if (tid < 200) bsum = b_ih[tid] + b_hh[tid];
    asm volatile("s_waitcnt vmcnt(0)" ::: "memory");  // weights resident
    __builtin_amdgcn_sched_barrier(0);

    if (tid < 200) {
        const int wr = 4 * (tid % NH) + (tid / NH);   // quad-permuted position
        float* xpb = xp + ((size_t)b * tcAlloc + (rt0 - t0)) * 200 + wr;
        int xr0 = __builtin_amdgcn_readfirstlane(xrow[0]);
        int xr1 = __builtin_amdgcn_readfirstlane(xrow[1]);
        for (int row = 0; row < nrows; row += 2) {
            const f32x2* e0 = (const f32x2*)(emb_table + (size_t)xr0 * ND); // 8B-aligned
            const f32x2* e1 = (const f32x2*)(emb_table + (size_t)xr1 * ND);
            const int nr = (row + 2 < nrows) ? row + 2 : 0;   // wrap: harmless re-read
            int nx0 = __builtin_amdgcn_readfirstlane(xrow[nr]);
            int nx1 = __builtin_amdgcn_readfirstlane(xrow[nr + 1]);
            f32x2 A01 = {bsum, 0.f}, A23 = {0.f, 0.f};
            f32x2 B01 = {bsum, 0.f}, B23 = {0.f, 0.f};
            KP2(0) KP2(1) KP2(2) KP2(3) KP2(4) KP2(5)
            KP2(6) KP2(7) KP2(8) KP2(9) KP2(10) KP2(11)
            A01 = FMA2(e0[24], w12.xy, A01);          // tail: e48->a0, e49->a1
            B01 = FMA2(e1[24], w12.xy, B01);
            xpb[(size_t)row * 200]       = (A01.x + A01.y) + (A23.x + A23.y);
            xpb[(size_t)(row + 1) * 200] = (B01.x + B01.y) + (B23.x + B23.y);
            xr0 = nx0; xr1 = nx1;
        }
    }
}

// ---------------- K2: 4 waves x 1 gate/lane (R13 verbatim) + fused k3 epilogue -----------
#define CDOT1(SEED,OUT) { f32x2 A01 = {(SEED), 0.f}, A23 = {0.f, 0.f};        \
    A01=FMA2(hp0 ,CW_0.xy ,A01); A23=FMA2(hp1 ,CW_0.zw ,A23);                 \
    A01=FMA2(hp2 ,CW_1.xy ,A01); A23=FMA2(hp3 ,CW_1.zw ,A23);                 \
    A01=FMA2(hp4 ,CW_2.xy ,A01); A23=FMA2(hp5 ,CW_2.zw ,A23);                 \
    A01=FMA2(hp6 ,CW_3.xy ,A01); A23=FMA2(hp7 ,CW_3.zw ,A23);                 \
    A01=FMA2(hp8 ,CW_4.xy ,A01); A23=FMA2(hp9 ,CW_4.zw ,A23);                 \
    A01=FMA2(hp10,CW_5.xy ,A01); A23=FMA2(hp11,CW_5.zw ,A23);                 \
    A01=FMA2(hp12,CW_6.xy ,A01); A23=FMA2(hp13,CW_6.zw ,A23);                 \
    A01=FMA2(hp14,CW_7.xy ,A01); A23=FMA2(hp15,CW_7.zw ,A23);                 \
    A01=FMA2(hp16,CW_8.xy ,A01); A23=FMA2(hp17,CW_8.zw ,A23);                 \
    A01=FMA2(hp18,CW_9.xy ,A01); A23=FMA2(hp19,CW_9.zw ,A23);                 \
    A01=FMA2(hp20,CW_10.xy,A01); A23=FMA2(hp21,CW_10.zw,A23);                 \
    A01=FMA2(hp22,CW_11.xy,A01); A23=FMA2(hp23,CW_11.zw,A23);                 \
    A23=FMA2(hp24,CW_12.xy,A23);                                              \
    OUT = (A01.x + A01.y) + (A23.x + A23.y); }

#define SSTEP(XQ, S) {                                                        \
    f32x2 hp0 ={rdl(hv,0 ),rdl(hv,1 )}, hp1 ={rdl(hv,2 ),rdl(hv,3 )};         \
    f32x2 hp2 ={rdl(hv,4 ),rdl(hv,5 )}, hp3 ={rdl(hv,6 ),rdl(hv,7 )};         \
    f32x2 hp4 ={rdl(hv,8 ),rdl(hv,9 )}, hp5 ={rdl(hv,10),rdl(hv,11)};         \
    f32x2 hp6 ={rdl(hv,12),rdl(hv,13)}, hp7 ={rdl(hv,14),rdl(hv,15)};         \
    f32x2 hp8 ={rdl(hv,16),rdl(hv,17)}, hp9 ={rdl(hv,18),rdl(hv,19)};         \
    f32x2 hp10={rdl(hv,20),rdl(hv,21)}, hp11={rdl(hv,22),rdl(hv,23)};         \
    f32x2 hp12={rdl(hv,24),rdl(hv,25)}, hp13={rdl(hv,26),rdl(hv,27)};         \
    f32x2 hp14={rdl(hv,28),rdl(hv,29)}, hp15={rdl(hv,30),rdl(hv,31)};         \
    f32x2 hp16={rdl(hv,32),rdl(hv,33)}, hp17={rdl(hv,34),rdl(hv,35)};         \
    f32x2 hp18={rdl(hv,36),rdl(hv,37)}, hp19={rdl(hv,38),rdl(hv,39)};         \
    f32x2 hp20={rdl(hv,40),rdl(hv,41)}, hp21={rdl(hv,42),rdl(hv,43)};         \
    f32x2 hp22={rdl(hv,44),rdl(hv,45)}, hp23={rdl(hv,46),rdl(hv,47)};         \
    f32x2 hp24={rdl(hv,48),rdl(hv,49)};                                       \
    float gg;                                                                 \
    CDOT1(XQ, gg)                                                             \
    { int sn_ = (S) + 4; if (sn_ > nsteps - 1) sn_ = nsteps - 1;              \
      XQ = xpb[(size_t)sn_ * 200]; }                                          \
    float act = fmaf(rcpf(1.f + __expf(-sce * gg)), sce, ade);                \
    abuf[(S) & 1][wid][kln] = act;                                            \
    FENCE_BAR                                                                 \
    float i_ = abuf[(S) & 1][0][kln];                                         \
    float f_ = abuf[(S) & 1][1][kln];                                         \
    float gt = abuf[(S) & 1][2][kln];                                         \
    float o_ = abuf[(S) & 1][3][kln];                                         \
    cst = fmaf(f_, cst, i_ * gt);                                             \
    float th = fmaf(rcpf(1.f + __expf(-2.f * cst)), 2.f, -1.f);               \
    hv = o_ * th;                                                             \
    hkeep = (t0 + (S) == lastidx) ? hv : hkeep;                               \
}

__global__ __launch_bounds__(256)
__attribute__((amdgpu_waves_per_eu(1, 1)))   // 4 waves -> 1 per SIMD, full budgets
void k2_scan(const int* __restrict__ x, const int* __restrict__ lengths,
             const float* __restrict__ emb_table,
             const float* __restrict__ wsWhh, const float* __restrict__ xp,
             const float* __restrict__ W_lin, const float* __restrict__ b_lin,
             float* __restrict__ stH, float* __restrict__ stC, float* __restrict__ lastH,
             float* __restrict__ out, int t0, int t1, int tcAlloc)
{
    const int b   = blockIdx.x, tid = threadIdx.x;
    const int wid = tid >> 6;                  // gate q: 0=i 1=f 2=g 3=o
    const int kln = tid & 63;                  // lane = hidden unit
    const int kc  = (kln < NH) ? kln : NH - 1; // lanes 50-63 shadow unit 49 (harmless dup)

    __shared__ __align__(16) float abuf[2][4][64];  // [parity][gate][lane] acts, 2KB
    __shared__ int xv[NT];                          // epilogue: token ids
    __shared__ float ps[5][52], pm[5][52];          // epilogue: pooling partials
    __shared__ float rep[160];                      // epilogue: concat vector

    const int lastidx = min(lengths[b], NT) - 1;
    const int nsteps  = t1 - t0;

    // all 4 waves hold identical (hv, cst) per lane -> h broadcast stays in-wave (readlane)
    float hv  = (t0 == 0) ? 0.f : stH[b * NH + kc];
    float cst = (t0 == 0) ? 0.f : stC[b * NH + kc];

    // weights: ONE gate row = 13 aligned dwordx4 = 52 VGPRs (fits under the ~132 cap)
    DECLROW(CW)
    LOADROW(CW, wsWhh + ((size_t)wid * NH + kc) * 52)
    asm volatile("s_waitcnt vmcnt(0)" ::: "memory");
    __builtin_amdgcn_sched_barrier(0);

    const float sce = (wid == 2) ? 2.f : 1.f;      // gate g: tanh(x)=2*sigmoid(2x)-1
    const float ade = (wid == 2) ? -1.f : 0.f;     // sigmoid: fma(r,1,0)==r bitwise

    // xq: one float per step (quad-permuted slot 4k+q), 4-deep compiler rotation
    const float* xpb = xp + (size_t)b * tcAlloc * 200 + 4 * kc + wid;
    float xq0 = xpb[0];
    float xq1 = xpb[200];
    float xq2 = xpb[400];
    float xq3 = xpb[600];
    float hkeep = 0.f;

    for (int s4 = 0; s4 < nsteps; s4 += 4) {
        SSTEP(xq0, s4 + 0)
        SSTEP(xq1, s4 + 1)
        SSTEP(xq2, s4 + 2)
        SSTEP(xq3, s4 + 3)
    }

    if (wid == 0 && kln < NH) {
        stH[b * NH + kln] = hv;
        stC[b * NH + kln] = cst;
        if (lastidx >= t0 && lastidx < t1) lastH[b * NH + kln] = hkeep;
    }

    // -------- fused k3 epilogue (final chunk only; t1 is a kernel arg -> uniform) --------
    if (t1 == NT) {
        for (int i = tid; i < NT; i += 256) xv[i] = x[(size_t)b * NT + i];
        __syncthreads();
        const int g5 = tid / ND, d5 = tid - g5 * ND;
        if (tid < 250) {
            float s = 0.f, m = -INFINITY;
            #pragma unroll 4
            for (int t = g5; t < NT; t += 5) {
                float e = emb_table[(size_t)xv[t] * ND + d5];
                s += e; m = fmaxf(m, e);
            }
            ps[g5][d5] = s; pm[g5][d5] = m;
        }
        __syncthreads();
        if (tid < NH) {
            float s = ps[0][tid] + ps[1][tid] + ps[2][tid] + ps[3][tid] + ps[4][tid];
            float m = fmaxf(fmaxf(fmaxf(pm[0][tid], pm[1][tid]),
                                  fmaxf(pm[2][tid], pm[3][tid])), pm[4][tid]);
            rep[tid]          = (lastidx >= t0) ? hkeep : lastH[b * NH + tid];
            rep[NH + tid]     = s / (float)lengths[b];
            rep[2 * NH + tid] = m;
        }
        __syncthreads();
        if (tid < NC) {
            float acc = b_lin[tid];
            #pragma unroll 5
            for (int j = 0; j < 3 * NH; ++j)
                acc = fmaf(rep[j], W_lin[tid * 3 * NH + j], acc);
            out[(size_t)b * NC + tid] = acc;
        }
    }
}

extern "C" void kernel_launch(void* const* d_in, const int* in_sizes, int n_in,
                              void* d_out, int out_size, void* d_ws, size_t ws_size,
                              hipStream_t stream) {
    const int*   x     = (const int*)d_in[0];
    const int*   len   = (const int*)d_in[1];
    const float* emb   = (const float*)d_in[3];
    const float* W_ih  = (const float*)d_in[4];
    const float* W_hh  = (const float*)d_in[5];
    const float* b_ih  = (const float*)d_in[6];
    const float* b_hh  = (const float*)d_in[7];
    const float* W_lin = (const float*)d_in[8];
    const float* b_lin = (const float*)d_in[9];
    float* outp = (float*)d_out;

    // ws: [stH][stC][lastH] | @160KB: wsWih[200*52], wsWhh[200*52] | @256KB: xp (+8KB slack)
    float* stH   = (float*)d_ws;
    float* stC   = stH + NB * NH;
    float* lastH = stC + NB * NH;
    float* wsWih = (float*)((char*)d_ws + 160 * 1024);
    float* wsWhh = wsWih + 200 * 52;
    const size_t xpOff = 256 * 1024;
    float* xp = (float*)((char*)d_ws + xpOff);

    size_t avail = (ws_size > xpOff + 8192) ? ws_size - xpOff - 8192 : 0;
    int tc = (int)(avail / ((size_t)NB * 200 * sizeof(float)));
    tc &= ~3;                 // chunks are multiples of 4 (NT=512 -> every chunk too)
    if (tc > NT) tc = NT;
    if (tc < 4)  tc = 4;

    hipLaunchKernelGGL(k0_prep, dim3(82), dim3(256), 0, stream, W_hh, W_ih, wsWih, wsWhh);

    for (int t0 = 0; t0 < NT; t0 += tc) {
        const int t1 = min(NT, t0 + tc);
        const int tiles = (t1 - t0 + 63) / 64;
        hipLaunchKernelGGL(k1_xproj, dim3(NB * tiles), dim3(256), 0, stream,
                           x, len, emb, wsWih, b_ih, b_hh, xp, t0, t1, tiles, tc);
        hipLaunchKernelGGL(k2_scan, dim3(NB), dim3(256), 0, stream,
                           x, len, emb, wsWhh, xp, W_lin, b_lin,
                           stH, stC, lastH, outp, t0, t1, tc);
    }
}